// Round 1
// baseline (1759.374 us; speedup 1.0000x reference)
//
#include <hip/hip_runtime.h>
#include <math.h>

#define NB 256
#define TT 64
#define DD 1024
#define HH 1024

typedef __attribute__((ext_vector_type(8))) short short8;
typedef __attribute__((ext_vector_type(4))) float floatx4;

__device__ inline unsigned short f2bf(float f) {
    unsigned int u = __builtin_bit_cast(unsigned int, f);
    u += 0x7fffu + ((u >> 16) & 1u);
    return (unsigned short)(u >> 16);
}
__device__ inline float bf2f(unsigned int h16) {
    unsigned int u = h16 << 16;
    return __builtin_bit_cast(float, u);
}

// ---------------- conv W: fp32 [k][4096] -> bf16 B-fragment tiles, N_b=64 ----------
// Tile (nj 0..63, kc 0..47): 512 units of 16B; unit = kq*64 + cc (kq 0..7, cc 0..63);
// holds W[k = kc*64+kq*8 + j][col = (cc>>4)*1024 + nj*16 + (cc&15)], j=0..7.
__global__ void k_convW(const float* __restrict__ Wh,
                        const float* __restrict__ Wattn,
                        const float* __restrict__ Wx,
                        unsigned short* __restrict__ Wsw) {
    int u = blockIdx.x * 256 + threadIdx.x;  // 0 .. 64*48*512-1
    int tile = u >> 9;
    int nj = tile / 48, kc = tile % 48;
    int within = u & 511;
    int kq = within >> 6, cc = within & 63;
    int k = kc * 64 + kq * 8;
    int col = (cc >> 4) * 1024 + nj * 16 + (cc & 15);
    const float* src;
    if (k < 1024)       src = Wh    + (size_t)k * 4096 + col;
    else if (k < 2048)  src = Wattn + (size_t)(k - 1024) * 4096 + col;
    else                src = Wx    + (size_t)(k - 2048) * 4096 + col;
    unsigned int w[4];
#pragma unroll
    for (int j = 0; j < 4; ++j) {
        unsigned int lo = f2bf(src[(size_t)(2 * j) * 4096]);
        unsigned int hi = f2bf(src[(size_t)(2 * j + 1) * 4096]);
        w[j] = lo | (hi << 16);
    }
    ((uint4*)Wsw)[u] = make_uint4(w[0], w[1], w[2], w[3]);
}

// ---------------- conv x: fp32 [m][t][d] -> bf16 A-fragment layout -----------------
// xF unit index = t*32768 + kq*256 + m ; holds x[m][t][kq*8 + j], j=0..7.
// LDS-transpose version: coalesced float4 row reads -> bf16 LDS tile ->
// coalesced fragment-order uint4 writes. (Old version read at 256KB lane stride:
// 2x over-fetch, 36% BW.)
__global__ __launch_bounds__(256) void k_convX(const float* __restrict__ x,
                                               unsigned short* __restrict__ xF) {
    const int t  = blockIdx.x >> 4;   // 0..63
    const int mb = blockIdx.x & 15;   // 0..15 (16 batch rows per block)
    const int tid = threadIdx.x;
    __shared__ unsigned short xb[16][1032];  // row stride 1032 shorts = 2064 B (pad)

    // phase 1: 16 rows, each read fully coalesced (256 thr x float4 = 4 KB)
#pragma unroll
    for (int mm = 0; mm < 16; ++mm) {
        int m = mb * 16 + mm;
        const float4* src = (const float4*)(x + (size_t)m * (TT * DD) + (size_t)t * DD);
        float4 v = src[tid];  // d = tid*4 .. tid*4+3
        unsigned int w0 = f2bf(v.x) | (f2bf(v.y) << 16);
        unsigned int w1 = f2bf(v.z) | (f2bf(v.w) << 16);
        *(uint2*)&xb[mm][tid * 4] = make_uint2(w0, w1);
    }
    __syncthreads();

    // phase 2: write 2048 units (kq 0..127 x mm 0..15) in output order, 16B/thread
#pragma unroll
    for (int i = 0; i < 8; ++i) {
        int u = i * 256 + tid;
        int kq = u >> 4, mm = u & 15;
        uint4 val = *(const uint4*)&xb[mm][kq * 8];
        size_t gu = (size_t)t * 32768 + (size_t)kq * 256 + mb * 16 + mm;
        ((uint4*)xF)[gu] = val;
    }
}

// ---------------- conv A -> bf16, plus h0 = c0 = mean ----------------
__global__ void k_convA_init(const float* __restrict__ A,
                             unsigned short* __restrict__ Abf,
                             float* __restrict__ h0,
                             float* __restrict__ c) {
    int idx = blockIdx.x * 256 + threadIdx.x;  // n*1024 + h
    const float4* ap = (const float4*)(A + (size_t)idx * 16);
    float4 v0 = ap[0], v1 = ap[1], v2 = ap[2], v3 = ap[3];
    float vs[16] = {v0.x, v0.y, v0.z, v0.w, v1.x, v1.y, v1.z, v1.w,
                    v2.x, v2.y, v2.z, v2.w, v3.x, v3.y, v3.z, v3.w};
    float s = 0.f;
    unsigned int w[8];
#pragma unroll
    for (int j = 0; j < 8; ++j) {
        s += vs[2 * j] + vs[2 * j + 1];
        w[j] = f2bf(vs[2 * j]) | (f2bf(vs[2 * j + 1]) << 16);
    }
    ((uint4*)Abf)[idx * 2]     = make_uint4(w[0], w[1], w[2], w[3]);
    ((uint4*)Abf)[idx * 2 + 1] = make_uint4(w[4], w[5], w[6], w[7]);
    s *= (1.f / 16.f);
    h0[idx] = s;
    c[idx] = s;
}

// ---------------- k_attn: attention + write h/attn into lhs fragment buffer ----------
// lhsF unit = kq*256 + n (kq 0..127 = h features, 128..255 = attn features)
__global__ __launch_bounds__(256) void k_attn(
    const unsigned short* __restrict__ Abf,
    const float* __restrict__ hprev, int hstride,
    unsigned short* __restrict__ lhsF) {
    const int n = blockIdx.x;
    const int tid = threadIdx.x;
    const int lane = tid & 63, wave = tid >> 6;

    float4 hv = *(const float4*)(hprev + (size_t)n * hstride + tid * 4);
    const uint4* ar = (const uint4*)(Abf + ((size_t)n * 1024 + tid * 4) * 16);

    float a[4][16];
#pragma unroll
    for (int r = 0; r < 4; ++r) {
        uint4 p0 = ar[r * 2], p1 = ar[r * 2 + 1];
        unsigned int ws[8] = {p0.x, p0.y, p0.z, p0.w, p1.x, p1.y, p1.z, p1.w};
#pragma unroll
        for (int j = 0; j < 8; ++j) {
            a[r][2 * j]     = bf2f(ws[j] & 0xffffu);
            a[r][2 * j + 1] = bf2f(ws[j] >> 16);
        }
    }
    float hvv[4] = {hv.x, hv.y, hv.z, hv.w};
    float s[16];
#pragma unroll
    for (int l = 0; l < 16; ++l) {
        float t = 0.f;
#pragma unroll
        for (int r = 0; r < 4; ++r) t += hvv[r] * a[r][l];
        s[l] = t;
    }

#pragma unroll
    for (int off = 32; off > 0; off >>= 1) {
#pragma unroll
        for (int l = 0; l < 16; ++l) s[l] += __shfl_xor(s[l], off, 64);
    }
    __shared__ float wred[4 * 16];
    if (lane == 0) {
#pragma unroll
        for (int l = 0; l < 16; ++l) wred[wave * 16 + l] = s[l];
    }
    __syncthreads();

    const float scale = 0.03125f;  // 1/sqrt(1024)
    float sv[16];
#pragma unroll
    for (int l = 0; l < 16; ++l)
        sv[l] = (wred[l] + wred[16 + l] + wred[32 + l] + wred[48 + l]) * scale;
    float mx = sv[0];
#pragma unroll
    for (int l = 1; l < 16; ++l) mx = fmaxf(mx, sv[l]);
    float e[16], sum = 0.f;
#pragma unroll
    for (int l = 0; l < 16; ++l) { e[l] = __expf(sv[l] - mx); sum += e[l]; }
    float inv = 1.f / sum;
#pragma unroll
    for (int l = 0; l < 16; ++l) e[l] *= inv;

    unsigned short hb[4], ab[4];
#pragma unroll
    for (int r = 0; r < 4; ++r) {
        float acc = 0.f;
#pragma unroll
        for (int l = 0; l < 16; ++l) acc += a[r][l] * e[l];
        ab[r] = f2bf(acc);
        hb[r] = f2bf(hvv[r]);
    }
    unsigned int hw0 = (unsigned int)hb[0] | ((unsigned int)hb[1] << 16);
    unsigned int hw1 = (unsigned int)hb[2] | ((unsigned int)hb[3] << 16);
    unsigned int aw0 = (unsigned int)ab[0] | ((unsigned int)ab[1] << 16);
    unsigned int aw1 = (unsigned int)ab[2] | ((unsigned int)ab[3] << 16);
    size_t hu = ((size_t)(tid >> 1) * 256 + n) * 8 + (size_t)(tid & 1) * 4;
    size_t au = ((size_t)(128 + (tid >> 1)) * 256 + n) * 8 + (size_t)(tid & 1) * 4;
    *(uint2*)(lhsF + hu) = make_uint2(hw0, hw1);
    *(uint2*)(lhsF + au) = make_uint2(aw0, aw1);
}

// ---------------- k_step: LDS-free bf16 MFMA GEMM + LSTM gates ---------------------
// grid (64, 4): nj (16 j x 4 gates = 64 cols), mi (64 rows). 256 thr = 4 waves.
// NEW STRUCTURE: waves split K (each wave owns a disjoint K-quarter of 768 = 12
// chunks of 64) and compute the FULL 64x64 tile for it, loading A and B fragments
// DIRECT global->VGPR (operand buffers are already in fragment order; the old
// stage-to-LDS/read-from-LDS pair was an identity map costing 48 KB LDS traffic
// per chunk vs 16 KB streamed). No barriers in the K-loop; 2-deep register double
// buffer; compiler pipelines freely. LDS used once at the end to sum the 4
// per-wave fp32 partials + apply gates.
__global__ __launch_bounds__(256) void k_step(
    const unsigned short* __restrict__ lhsF,
    const unsigned short* __restrict__ xFt,   // xF + t*262144
    const unsigned short* __restrict__ Wsw,
    const float* __restrict__ b,
    float* __restrict__ c,
    float* __restrict__ out_t) {              // out + t*HH, row stride TT*HH
    const int nj = blockIdx.x, mi = blockIdx.y;
    const int tid = threadIdx.x;
    const int lane = tid & 63, wave = tid >> 6;
    const int l15 = lane & 15, quad = lane >> 4;

    floatx4 acc[4][4];
#pragma unroll
    for (int mt = 0; mt < 4; ++mt)
#pragma unroll
        for (int nt = 0; nt < 4; ++nt) acc[mt][nt] = (floatx4)0.f;

    const unsigned short* wTile = Wsw + (size_t)nj * (48 * 512 * 8);

    // A unit (kc*8 + kq)*256 + m  (kc<32: lhsF h|attn, kc>=32: xF x_t)
    auto aBase = [&](int kc) -> const unsigned short* {
        return (kc < 32)
            ? lhsF + ((size_t)(kc * 8) * 256 + (size_t)mi * 64) * 8
            : xFt + ((size_t)((kc - 32) * 8) * 256 + (size_t)mi * 64) * 8;
    };

    short8 A0[8], B0[8], A1[8], B1[8];

    // per chunk: 8 A-frag + 8 B-frag dwordx4 loads (each 4x256B coalesced segments)
#define LOADCH(Ar, Br, kc)                                                          \
    do {                                                                            \
        const unsigned short* ab_ = aBase(kc);                                      \
        const unsigned short* bb_ = wTile + (size_t)(kc) * 4096;                    \
        _Pragma("unroll") for (int mt = 0; mt < 4; ++mt)                            \
            _Pragma("unroll") for (int ks = 0; ks < 2; ++ks)                        \
                Ar[mt * 2 + ks] = *(const short8*)(ab_ +                            \
                    (size_t)((ks * 4 + quad) * 256 + mt * 16 + l15) * 8);           \
        _Pragma("unroll") for (int nt = 0; nt < 4; ++nt)                            \
            _Pragma("unroll") for (int ks = 0; ks < 2; ++ks)                        \
                Br[nt * 2 + ks] = *(const short8*)(bb_ +                            \
                    (size_t)((ks * 4 + quad) * 64 + nt * 16 + l15) * 8);            \
    } while (0)

#define MMAC(Ar, Br)                                                                \
    do {                                                                            \
        _Pragma("unroll") for (int mt = 0; mt < 4; ++mt)                            \
            _Pragma("unroll") for (int nt = 0; nt < 4; ++nt) {                      \
                acc[mt][nt] = __builtin_amdgcn_mfma_f32_16x16x32_bf16(              \
                    Ar[mt * 2 + 0], Br[nt * 2 + 0], acc[mt][nt], 0, 0, 0);          \
                acc[mt][nt] = __builtin_amdgcn_mfma_f32_16x16x32_bf16(              \
                    Ar[mt * 2 + 1], Br[nt * 2 + 1], acc[mt][nt], 0, 0, 0);          \
            }                                                                       \
    } while (0)

    const int kc0 = wave * 12;  // each wave: chunks kc0 .. kc0+11
    LOADCH(A0, B0, kc0);
#pragma unroll
    for (int i = 0; i < 6; ++i) {
        LOADCH(A1, B1, kc0 + 2 * i + 1);
        MMAC(A0, B0);
        if (i < 5) LOADCH(A0, B0, kc0 + 2 * i + 2);
        MMAC(A1, B1);
    }
#undef LOADCH
#undef MMAC

    // epilogue: sum the 4 per-wave 64x64 fp32 partials in LDS, then gates + c/h
    __shared__ float red[4][4096];  // 64 KB
#pragma unroll
    for (int mt = 0; mt < 4; ++mt)
#pragma unroll
        for (int nt = 0; nt < 4; ++nt)
#pragma unroll
            for (int r = 0; r < 4; ++r) {
                int row = mt * 16 + quad * 4 + r;
                int cc = nt * 16 + l15;
                red[wave][row * 64 + cc] = acc[mt][nt][r];
            }
    __syncthreads();

    const int j15 = tid & 15;
    const int jj = nj * 16 + j15;
    const float bi = b[jj], bf_ = b[1024 + jj], bo = b[2048 + jj], bg = b[3072 + jj];
#pragma unroll
    for (int i = 0; i < 4; ++i) {
        int cell = i * 256 + tid;
        int row = cell >> 4;
        float ai = bi, af2 = bf_, ao = bo, ag = bg;
#pragma unroll
        for (int w = 0; w < 4; ++w) {
            ai  += red[w][row * 64 + j15];
            af2 += red[w][row * 64 + 16 + j15];
            ao  += red[w][row * 64 + 32 + j15];
            ag  += red[w][row * 64 + 48 + j15];
        }
        float iv = 1.f / (1.f + __expf(-ai));
        float fv = 1.f / (1.f + __expf(-af2));
        float ov = 1.f / (1.f + __expf(-ao));
        float gv = 1.f - 2.f / (__expf(2.f * ag) + 1.f);
        int n = mi * 64 + row;
        size_t ci = (size_t)n * HH + jj;
        float cold = c[ci];
        float cn = fv * cold + iv * gv;
        c[ci] = cn;
        float th = 1.f - 2.f / (__expf(2.f * cn) + 1.f);
        out_t[(size_t)n * (TT * HH) + jj] = ov * th;
    }
}

extern "C" void kernel_launch(void* const* d_in, const int* in_sizes, int n_in,
                              void* d_out, int out_size, void* d_ws, size_t ws_size,
                              hipStream_t stream) {
    const float* x     = (const float*)d_in[0];
    const float* A     = (const float*)d_in[1];
    const float* Wx    = (const float*)d_in[2];
    const float* Wh    = (const float*)d_in[3];
    const float* Wattn = (const float*)d_in[4];
    const float* b     = (const float*)d_in[5];
    float* out = (float*)d_out;

    char* w = (char*)d_ws;
    unsigned short* Wsw  = (unsigned short*)(w);                 // 25,165,824 B
    unsigned short* xF   = (unsigned short*)(w + 25165824);      // 33,554,432 B
    unsigned short* lhsF = (unsigned short*)(w + 58720256);      //  1,048,576 B
    unsigned short* Abf  = (unsigned short*)(w + 59768832);      //  8,388,608 B
    float* h0            = (float*)(w + 68157440);               //  1,048,576 B
    float* c             = (float*)(w + 69206016);               //  1,048,576 B

    k_convW<<<6144, 256, 0, stream>>>(Wh, Wattn, Wx, Wsw);
    k_convX<<<1024, 256, 0, stream>>>(x, xF);
    k_convA_init<<<1024, 256, 0, stream>>>(A, Abf, h0, c);

    for (int t = 0; t < TT; ++t) {
        const float* hprev = (t == 0) ? h0 : out + (size_t)(t - 1) * HH;
        int hstride = (t == 0) ? HH : TT * HH;
        k_attn<<<NB, 256, 0, stream>>>(Abf, hprev, hstride, lhsF);
        k_step<<<dim3(64, 4), 256, 0, stream>>>(
            lhsF, xF + (size_t)t * 262144, Wsw, b, c, out + (size_t)t * HH);
    }
}

// Round 2
// 1495.611 us; speedup vs baseline: 1.1764x; 1.1764x over previous
//
#include <hip/hip_runtime.h>
#include <math.h>

#define NB 256
#define TT 64
#define DD 1024
#define HH 1024

typedef __attribute__((ext_vector_type(8))) short short8;
typedef __attribute__((ext_vector_type(4))) float floatx4;

__device__ inline unsigned short f2bf(float f) {
    unsigned int u = __builtin_bit_cast(unsigned int, f);
    u += 0x7fffu + ((u >> 16) & 1u);
    return (unsigned short)(u >> 16);
}
__device__ inline float bf2f(unsigned int h16) {
    unsigned int u = h16 << 16;
    return __builtin_bit_cast(float, u);
}

// ---------------- conv W: fp32 [k][4096] -> bf16 B-fragment tiles, N_b=64 ----------
// Tile (nj 0..63, kc 0..47): 512 units of 16B; unit = kq*64 + cc (kq 0..7, cc 0..63);
// holds W[k = kc*64+kq*8 + j][col = (cc>>4)*1024 + nj*16 + (cc&15)], j=0..7.
__global__ void k_convW(const float* __restrict__ Wh,
                        const float* __restrict__ Wattn,
                        const float* __restrict__ Wx,
                        unsigned short* __restrict__ Wsw) {
    int u = blockIdx.x * 256 + threadIdx.x;  // 0 .. 64*48*512-1
    int tile = u >> 9;
    int nj = tile / 48, kc = tile % 48;
    int within = u & 511;
    int kq = within >> 6, cc = within & 63;
    int k = kc * 64 + kq * 8;
    int col = (cc >> 4) * 1024 + nj * 16 + (cc & 15);
    const float* src;
    if (k < 1024)       src = Wh    + (size_t)k * 4096 + col;
    else if (k < 2048)  src = Wattn + (size_t)(k - 1024) * 4096 + col;
    else                src = Wx    + (size_t)(k - 2048) * 4096 + col;
    unsigned int w[4];
#pragma unroll
    for (int j = 0; j < 4; ++j) {
        unsigned int lo = f2bf(src[(size_t)(2 * j) * 4096]);
        unsigned int hi = f2bf(src[(size_t)(2 * j + 1) * 4096]);
        w[j] = lo | (hi << 16);
    }
    ((uint4*)Wsw)[u] = make_uint4(w[0], w[1], w[2], w[3]);
}

// ---------------- conv x: fp32 [m][t][d] -> bf16 A-fragment layout -----------------
// xF unit index = t*32768 + kq*256 + m ; holds x[m][t][kq*8 + j], j=0..7.
// LDS-transpose: coalesced float4 row reads -> bf16 LDS tile -> coalesced
// fragment-order uint4 writes.
__global__ __launch_bounds__(256) void k_convX(const float* __restrict__ x,
                                               unsigned short* __restrict__ xF) {
    const int t  = blockIdx.x >> 4;   // 0..63
    const int mb = blockIdx.x & 15;   // 0..15 (16 batch rows per block)
    const int tid = threadIdx.x;
    __shared__ unsigned short xb[16][1032];  // row stride 1032 shorts (pad)

#pragma unroll
    for (int mm = 0; mm < 16; ++mm) {
        int m = mb * 16 + mm;
        const float4* src = (const float4*)(x + (size_t)m * (TT * DD) + (size_t)t * DD);
        float4 v = src[tid];  // d = tid*4 .. tid*4+3
        unsigned int w0 = f2bf(v.x) | (f2bf(v.y) << 16);
        unsigned int w1 = f2bf(v.z) | (f2bf(v.w) << 16);
        *(uint2*)&xb[mm][tid * 4] = make_uint2(w0, w1);
    }
    __syncthreads();

#pragma unroll
    for (int i = 0; i < 8; ++i) {
        int u = i * 256 + tid;
        int kq = u >> 4, mm = u & 15;
        uint4 val = *(const uint4*)&xb[mm][kq * 8];
        size_t gu = (size_t)t * 32768 + (size_t)kq * 256 + mb * 16 + mm;
        ((uint4*)xF)[gu] = val;
    }
}

// ---------------- conv A -> bf16, plus h0 = c0 = mean ----------------
__global__ void k_convA_init(const float* __restrict__ A,
                             unsigned short* __restrict__ Abf,
                             float* __restrict__ h0,
                             float* __restrict__ c) {
    int idx = blockIdx.x * 256 + threadIdx.x;  // n*1024 + h
    const float4* ap = (const float4*)(A + (size_t)idx * 16);
    float4 v0 = ap[0], v1 = ap[1], v2 = ap[2], v3 = ap[3];
    float vs[16] = {v0.x, v0.y, v0.z, v0.w, v1.x, v1.y, v1.z, v1.w,
                    v2.x, v2.y, v2.z, v2.w, v3.x, v3.y, v3.z, v3.w};
    float s = 0.f;
    unsigned int w[8];
#pragma unroll
    for (int j = 0; j < 8; ++j) {
        s += vs[2 * j] + vs[2 * j + 1];
        w[j] = f2bf(vs[2 * j]) | (f2bf(vs[2 * j + 1]) << 16);
    }
    ((uint4*)Abf)[idx * 2]     = make_uint4(w[0], w[1], w[2], w[3]);
    ((uint4*)Abf)[idx * 2 + 1] = make_uint4(w[4], w[5], w[6], w[7]);
    s *= (1.f / 16.f);
    h0[idx] = s;
    c[idx] = s;
}

// ---------------- k_attn: attention + write h/attn into lhs fragment buffer ----------
// lhsF unit = kq*256 + n (kq 0..127 = h features, 128..255 = attn features)
__global__ __launch_bounds__(256) void k_attn(
    const unsigned short* __restrict__ Abf,
    const float* __restrict__ hprev, int hstride,
    unsigned short* __restrict__ lhsF) {
    const int n = blockIdx.x;
    const int tid = threadIdx.x;
    const int lane = tid & 63, wave = tid >> 6;

    float4 hv = *(const float4*)(hprev + (size_t)n * hstride + tid * 4);
    const uint4* ar = (const uint4*)(Abf + ((size_t)n * 1024 + tid * 4) * 16);

    float a[4][16];
#pragma unroll
    for (int r = 0; r < 4; ++r) {
        uint4 p0 = ar[r * 2], p1 = ar[r * 2 + 1];
        unsigned int ws[8] = {p0.x, p0.y, p0.z, p0.w, p1.x, p1.y, p1.z, p1.w};
#pragma unroll
        for (int j = 0; j < 8; ++j) {
            a[r][2 * j]     = bf2f(ws[j] & 0xffffu);
            a[r][2 * j + 1] = bf2f(ws[j] >> 16);
        }
    }
    float hvv[4] = {hv.x, hv.y, hv.z, hv.w};
    float s[16];
#pragma unroll
    for (int l = 0; l < 16; ++l) {
        float t = 0.f;
#pragma unroll
        for (int r = 0; r < 4; ++r) t += hvv[r] * a[r][l];
        s[l] = t;
    }

#pragma unroll
    for (int off = 32; off > 0; off >>= 1) {
#pragma unroll
        for (int l = 0; l < 16; ++l) s[l] += __shfl_xor(s[l], off, 64);
    }
    __shared__ float wred[4 * 16];
    if (lane == 0) {
#pragma unroll
        for (int l = 0; l < 16; ++l) wred[wave * 16 + l] = s[l];
    }
    __syncthreads();

    const float scale = 0.03125f;  // 1/sqrt(1024)
    float sv[16];
#pragma unroll
    for (int l = 0; l < 16; ++l)
        sv[l] = (wred[l] + wred[16 + l] + wred[32 + l] + wred[48 + l]) * scale;
    float mx = sv[0];
#pragma unroll
    for (int l = 1; l < 16; ++l) mx = fmaxf(mx, sv[l]);
    float e[16], sum = 0.f;
#pragma unroll
    for (int l = 0; l < 16; ++l) { e[l] = __expf(sv[l] - mx); sum += e[l]; }
    float inv = 1.f / sum;
#pragma unroll
    for (int l = 0; l < 16; ++l) e[l] *= inv;

    unsigned short hb[4], ab[4];
#pragma unroll
    for (int r = 0; r < 4; ++r) {
        float acc = 0.f;
#pragma unroll
        for (int l = 0; l < 16; ++l) acc += a[r][l] * e[l];
        ab[r] = f2bf(acc);
        hb[r] = f2bf(hvv[r]);
    }
    unsigned int hw0 = (unsigned int)hb[0] | ((unsigned int)hb[1] << 16);
    unsigned int hw1 = (unsigned int)hb[2] | ((unsigned int)hb[3] << 16);
    unsigned int aw0 = (unsigned int)ab[0] | ((unsigned int)ab[1] << 16);
    unsigned int aw1 = (unsigned int)ab[2] | ((unsigned int)ab[3] << 16);
    size_t hu = ((size_t)(tid >> 1) * 256 + n) * 8 + (size_t)(tid & 1) * 4;
    size_t au = ((size_t)(128 + (tid >> 1)) * 256 + n) * 8 + (size_t)(tid & 1) * 4;
    *(uint2*)(lhsF + hu) = make_uint2(hw0, hw1);
    *(uint2*)(lhsF + au) = make_uint2(aw0, aw1);
}

// ---------------- k_step: 8-wave barrier-free direct-reg MFMA GEMM + gates ---------
// grid (64, 4): nj, mi. 512 thr = 8 INDEPENDENT waves (2 per SIMD), each owning a
// disjoint K-eighth (6 chunks of 64) of the 64x64 output tile, loading A/B
// fragments direct global->VGPR (operands pre-laid-out in fragment order).
// No barriers in the K-loop: one wave's vmcnt stall overlaps the sibling wave's
// MFMA issue on the same SIMD (round-1's regression was this exact structure at
// 1 wave/SIMD -- latency fully exposed). Per-CU traffic unchanged: 768 KB/step.
// Epilogue: waves 0-3 write fp32 partials to LDS, waves 4-7 add, then gates.
__global__ __launch_bounds__(512, 2) void k_step(
    const unsigned short* __restrict__ lhsF,
    const unsigned short* __restrict__ xFt,   // xF + t*262144
    const unsigned short* __restrict__ Wsw,
    const float* __restrict__ b,
    float* __restrict__ c,
    float* __restrict__ out_t) {              // out + t*HH, row stride TT*HH
    const int nj = blockIdx.x, mi = blockIdx.y;
    const int tid = threadIdx.x;
    const int lane = tid & 63, wave = tid >> 6;   // wave 0..7
    const int l15 = lane & 15, quad = lane >> 4;

    floatx4 acc[4][4];
#pragma unroll
    for (int mt = 0; mt < 4; ++mt)
#pragma unroll
        for (int nt = 0; nt < 4; ++nt) acc[mt][nt] = (floatx4)0.f;

    const unsigned short* wTile = Wsw + (size_t)nj * (48 * 512 * 8);

    // A unit (kc*8 + kq)*256 + m  (kc<32: lhsF h|attn, kc>=32: xF x_t)
    auto aBase = [&](int kc) -> const unsigned short* {
        return (kc < 32)
            ? lhsF + ((size_t)(kc * 8) * 256 + (size_t)mi * 64) * 8
            : xFt + ((size_t)((kc - 32) * 8) * 256 + (size_t)mi * 64) * 8;
    };

    short8 A0[8], B0[8], A1[8], B1[8];

#define LOADCH(Ar, Br, kc)                                                          \
    do {                                                                            \
        const unsigned short* ab_ = aBase(kc);                                      \
        const unsigned short* bb_ = wTile + (size_t)(kc) * 4096;                    \
        _Pragma("unroll") for (int mt = 0; mt < 4; ++mt)                            \
            _Pragma("unroll") for (int ks = 0; ks < 2; ++ks)                        \
                Ar[mt * 2 + ks] = *(const short8*)(ab_ +                            \
                    (size_t)((ks * 4 + quad) * 256 + mt * 16 + l15) * 8);           \
        _Pragma("unroll") for (int nt = 0; nt < 4; ++nt)                            \
            _Pragma("unroll") for (int ks = 0; ks < 2; ++ks)                        \
                Br[nt * 2 + ks] = *(const short8*)(bb_ +                            \
                    (size_t)((ks * 4 + quad) * 64 + nt * 16 + l15) * 8);            \
    } while (0)

#define MMAC(Ar, Br)                                                                \
    do {                                                                            \
        _Pragma("unroll") for (int mt = 0; mt < 4; ++mt)                            \
            _Pragma("unroll") for (int nt = 0; nt < 4; ++nt) {                      \
                acc[mt][nt] = __builtin_amdgcn_mfma_f32_16x16x32_bf16(              \
                    Ar[mt * 2 + 0], Br[nt * 2 + 0], acc[mt][nt], 0, 0, 0);          \
                acc[mt][nt] = __builtin_amdgcn_mfma_f32_16x16x32_bf16(              \
                    Ar[mt * 2 + 1], Br[nt * 2 + 1], acc[mt][nt], 0, 0, 0);          \
            }                                                                       \
    } while (0)

    const int kc0 = wave * 6;  // each wave: chunks kc0 .. kc0+5
    LOADCH(A0, B0, kc0);
#pragma unroll
    for (int i = 0; i < 3; ++i) {
        LOADCH(A1, B1, kc0 + 2 * i + 1);
        MMAC(A0, B0);
        if (i < 2) LOADCH(A0, B0, kc0 + 2 * i + 2);
        MMAC(A1, B1);
    }
#undef LOADCH
#undef MMAC

    // epilogue: merge 8 per-wave 64x64 fp32 partials through 64 KB LDS, then gates
    __shared__ float red[4][4096];  // 64 KB
    if (wave < 4) {
#pragma unroll
        for (int mt = 0; mt < 4; ++mt)
#pragma unroll
            for (int nt = 0; nt < 4; ++nt)
#pragma unroll
                for (int r = 0; r < 4; ++r) {
                    int row = mt * 16 + quad * 4 + r;
                    int cc = nt * 16 + l15;
                    red[wave][row * 64 + cc] = acc[mt][nt][r];
                }
    }
    __syncthreads();
    if (wave >= 4) {
#pragma unroll
        for (int mt = 0; mt < 4; ++mt)
#pragma unroll
            for (int nt = 0; nt < 4; ++nt)
#pragma unroll
                for (int r = 0; r < 4; ++r) {
                    int row = mt * 16 + quad * 4 + r;
                    int cc = nt * 16 + l15;
                    red[wave - 4][row * 64 + cc] += acc[mt][nt][r];
                }
    }
    __syncthreads();

    const int j15 = tid & 15;
    const int jj = nj * 16 + j15;
    const float bi = b[jj], bf_ = b[1024 + jj], bo = b[2048 + jj], bg = b[3072 + jj];
#pragma unroll
    for (int i = 0; i < 2; ++i) {
        int cell = i * 512 + tid;
        int row = cell >> 4;
        float ai = bi, af2 = bf_, ao = bo, ag = bg;
#pragma unroll
        for (int w = 0; w < 4; ++w) {
            ai  += red[w][row * 64 + j15];
            af2 += red[w][row * 64 + 16 + j15];
            ao  += red[w][row * 64 + 32 + j15];
            ag  += red[w][row * 64 + 48 + j15];
        }
        float iv = 1.f / (1.f + __expf(-ai));
        float fv = 1.f / (1.f + __expf(-af2));
        float ov = 1.f / (1.f + __expf(-ao));
        float gv = 1.f - 2.f / (__expf(2.f * ag) + 1.f);
        int n = mi * 64 + row;
        size_t ci = (size_t)n * HH + jj;
        float cold = c[ci];
        float cn = fv * cold + iv * gv;
        c[ci] = cn;
        float th = 1.f - 2.f / (__expf(2.f * cn) + 1.f);
        out_t[(size_t)n * (TT * HH) + jj] = ov * th;
    }
}

extern "C" void kernel_launch(void* const* d_in, const int* in_sizes, int n_in,
                              void* d_out, int out_size, void* d_ws, size_t ws_size,
                              hipStream_t stream) {
    const float* x     = (const float*)d_in[0];
    const float* A     = (const float*)d_in[1];
    const float* Wx    = (const float*)d_in[2];
    const float* Wh    = (const float*)d_in[3];
    const float* Wattn = (const float*)d_in[4];
    const float* b     = (const float*)d_in[5];
    float* out = (float*)d_out;

    char* w = (char*)d_ws;
    unsigned short* Wsw  = (unsigned short*)(w);                 // 25,165,824 B
    unsigned short* xF   = (unsigned short*)(w + 25165824);      // 33,554,432 B
    unsigned short* lhsF = (unsigned short*)(w + 58720256);      //  1,048,576 B
    unsigned short* Abf  = (unsigned short*)(w + 59768832);      //  8,388,608 B
    float* h0            = (float*)(w + 68157440);               //  1,048,576 B
    float* c             = (float*)(w + 69206016);               //  1,048,576 B

    k_convW<<<6144, 256, 0, stream>>>(Wh, Wattn, Wx, Wsw);
    k_convX<<<1024, 256, 0, stream>>>(x, xF);
    k_convA_init<<<1024, 256, 0, stream>>>(A, Abf, h0, c);

    for (int t = 0; t < TT; ++t) {
        const float* hprev = (t == 0) ? h0 : out + (size_t)(t - 1) * HH;
        int hstride = (t == 0) ? HH : TT * HH;
        k_attn<<<NB, 256, 0, stream>>>(Abf, hprev, hstride, lhsF);
        k_step<<<dim3(64, 4), 512, 0, stream>>>(
            lhsF, xF + (size_t)t * 262144, Wsw, b, c, out + (size_t)t * HH);
    }
}

// Round 3
// 1369.546 us; speedup vs baseline: 1.2846x; 1.0920x over previous
//
#include <hip/hip_runtime.h>
#include <math.h>

#define NB 256
#define TT 64
#define DD 1024
#define HH 1024

typedef __attribute__((ext_vector_type(8))) short short8;
typedef __attribute__((ext_vector_type(4))) float floatx4;

__device__ inline unsigned short f2bf(float f) {
    unsigned int u = __builtin_bit_cast(unsigned int, f);
    u += 0x7fffu + ((u >> 16) & 1u);
    return (unsigned short)(u >> 16);
}
__device__ inline float bf2f(unsigned int h16) {
    unsigned int u = h16 << 16;
    return __builtin_bit_cast(float, u);
}

__device__ inline void async_copy16(const unsigned short* g, unsigned short* l) {
    __builtin_amdgcn_global_load_lds(
        (const __attribute__((address_space(1))) unsigned int*)(g),
        (__attribute__((address_space(3))) unsigned int*)(l), 16, 0, 0);
}

// ---------------- conv W: fp32 [k][4096] -> bf16 B-fragment tiles, N_b=64 ----------
// Tile (nj 0..63, kc 0..47): 512 units of 16B; unit = kq*64 + cc (kq 0..7, cc 0..63);
// holds W[k = kc*64+kq*8 + j][col = (cc>>4)*1024 + nj*16 + (cc&15)], j=0..7.
__global__ void k_convW(const float* __restrict__ Wh,
                        const float* __restrict__ Wattn,
                        const float* __restrict__ Wx,
                        unsigned short* __restrict__ Wsw) {
    int u = blockIdx.x * 256 + threadIdx.x;  // 0 .. 64*48*512-1
    int tile = u >> 9;
    int nj = tile / 48, kc = tile % 48;
    int within = u & 511;
    int kq = within >> 6, cc = within & 63;
    int k = kc * 64 + kq * 8;
    int col = (cc >> 4) * 1024 + nj * 16 + (cc & 15);
    const float* src;
    if (k < 1024)       src = Wh    + (size_t)k * 4096 + col;
    else if (k < 2048)  src = Wattn + (size_t)(k - 1024) * 4096 + col;
    else                src = Wx    + (size_t)(k - 2048) * 4096 + col;
    unsigned int w[4];
#pragma unroll
    for (int j = 0; j < 4; ++j) {
        unsigned int lo = f2bf(src[(size_t)(2 * j) * 4096]);
        unsigned int hi = f2bf(src[(size_t)(2 * j + 1) * 4096]);
        w[j] = lo | (hi << 16);
    }
    ((uint4*)Wsw)[u] = make_uint4(w[0], w[1], w[2], w[3]);
}

// ---------------- conv x: fp32 [m][t][d] -> bf16 A-fragment layout -----------------
// xF unit index = t*32768 + kq*256 + m ; holds x[m][t][kq*8 + j], j=0..7.
// LDS-transpose: coalesced float4 row reads -> bf16 LDS tile -> coalesced
// fragment-order uint4 writes.
__global__ __launch_bounds__(256) void k_convX(const float* __restrict__ x,
                                               unsigned short* __restrict__ xF) {
    const int t  = blockIdx.x >> 4;   // 0..63
    const int mb = blockIdx.x & 15;   // 0..15 (16 batch rows per block)
    const int tid = threadIdx.x;
    __shared__ unsigned short xb[16][1032];  // row stride 1032 shorts (pad)

#pragma unroll
    for (int mm = 0; mm < 16; ++mm) {
        int m = mb * 16 + mm;
        const float4* src = (const float4*)(x + (size_t)m * (TT * DD) + (size_t)t * DD);
        float4 v = src[tid];  // d = tid*4 .. tid*4+3
        unsigned int w0 = f2bf(v.x) | (f2bf(v.y) << 16);
        unsigned int w1 = f2bf(v.z) | (f2bf(v.w) << 16);
        *(uint2*)&xb[mm][tid * 4] = make_uint2(w0, w1);
    }
    __syncthreads();

#pragma unroll
    for (int i = 0; i < 8; ++i) {
        int u = i * 256 + tid;
        int kq = u >> 4, mm = u & 15;
        uint4 val = *(const uint4*)&xb[mm][kq * 8];
        size_t gu = (size_t)t * 32768 + (size_t)kq * 256 + mb * 16 + mm;
        ((uint4*)xF)[gu] = val;
    }
}

// ---------------- conv A -> bf16, plus h0 = c0 = mean ----------------
__global__ void k_convA_init(const float* __restrict__ A,
                             unsigned short* __restrict__ Abf,
                             float* __restrict__ h0,
                             float* __restrict__ c) {
    int idx = blockIdx.x * 256 + threadIdx.x;  // n*1024 + h
    const float4* ap = (const float4*)(A + (size_t)idx * 16);
    float4 v0 = ap[0], v1 = ap[1], v2 = ap[2], v3 = ap[3];
    float vs[16] = {v0.x, v0.y, v0.z, v0.w, v1.x, v1.y, v1.z, v1.w,
                    v2.x, v2.y, v2.z, v2.w, v3.x, v3.y, v3.z, v3.w};
    float s = 0.f;
    unsigned int w[8];
#pragma unroll
    for (int j = 0; j < 8; ++j) {
        s += vs[2 * j] + vs[2 * j + 1];
        w[j] = f2bf(vs[2 * j]) | (f2bf(vs[2 * j + 1]) << 16);
    }
    ((uint4*)Abf)[idx * 2]     = make_uint4(w[0], w[1], w[2], w[3]);
    ((uint4*)Abf)[idx * 2 + 1] = make_uint4(w[4], w[5], w[6], w[7]);
    s *= (1.f / 16.f);
    h0[idx] = s;
    c[idx] = s;
}

// ---------------- k_attn: attention + write h/attn into lhs fragment buffer ----------
// lhsF unit = kq*256 + n (kq 0..127 = h features, 128..255 = attn features)
__global__ __launch_bounds__(256) void k_attn(
    const unsigned short* __restrict__ Abf,
    const float* __restrict__ hprev, int hstride,
    unsigned short* __restrict__ lhsF) {
    const int n = blockIdx.x;
    const int tid = threadIdx.x;
    const int lane = tid & 63, wave = tid >> 6;

    float4 hv = *(const float4*)(hprev + (size_t)n * hstride + tid * 4);
    const uint4* ar = (const uint4*)(Abf + ((size_t)n * 1024 + tid * 4) * 16);

    float a[4][16];
#pragma unroll
    for (int r = 0; r < 4; ++r) {
        uint4 p0 = ar[r * 2], p1 = ar[r * 2 + 1];
        unsigned int ws[8] = {p0.x, p0.y, p0.z, p0.w, p1.x, p1.y, p1.z, p1.w};
#pragma unroll
        for (int j = 0; j < 8; ++j) {
            a[r][2 * j]     = bf2f(ws[j] & 0xffffu);
            a[r][2 * j + 1] = bf2f(ws[j] >> 16);
        }
    }
    float hvv[4] = {hv.x, hv.y, hv.z, hv.w};
    float s[16];
#pragma unroll
    for (int l = 0; l < 16; ++l) {
        float t = 0.f;
#pragma unroll
        for (int r = 0; r < 4; ++r) t += hvv[r] * a[r][l];
        s[l] = t;
    }

#pragma unroll
    for (int off = 32; off > 0; off >>= 1) {
#pragma unroll
        for (int l = 0; l < 16; ++l) s[l] += __shfl_xor(s[l], off, 64);
    }
    __shared__ float wred[4 * 16];
    if (lane == 0) {
#pragma unroll
        for (int l = 0; l < 16; ++l) wred[wave * 16 + l] = s[l];
    }
    __syncthreads();

    const float scale = 0.03125f;  // 1/sqrt(1024)
    float sv[16];
#pragma unroll
    for (int l = 0; l < 16; ++l)
        sv[l] = (wred[l] + wred[16 + l] + wred[32 + l] + wred[48 + l]) * scale;
    float mx = sv[0];
#pragma unroll
    for (int l = 1; l < 16; ++l) mx = fmaxf(mx, sv[l]);
    float e[16], sum = 0.f;
#pragma unroll
    for (int l = 0; l < 16; ++l) { e[l] = __expf(sv[l] - mx); sum += e[l]; }
    float inv = 1.f / sum;
#pragma unroll
    for (int l = 0; l < 16; ++l) e[l] *= inv;

    unsigned short hb[4], ab[4];
#pragma unroll
    for (int r = 0; r < 4; ++r) {
        float acc = 0.f;
#pragma unroll
        for (int l = 0; l < 16; ++l) acc += a[r][l] * e[l];
        ab[r] = f2bf(acc);
        hb[r] = f2bf(hvv[r]);
    }
    unsigned int hw0 = (unsigned int)hb[0] | ((unsigned int)hb[1] << 16);
    unsigned int hw1 = (unsigned int)hb[2] | ((unsigned int)hb[3] << 16);
    unsigned int aw0 = (unsigned int)ab[0] | ((unsigned int)ab[1] << 16);
    unsigned int aw1 = (unsigned int)ab[2] | ((unsigned int)ab[3] << 16);
    size_t hu = ((size_t)(tid >> 1) * 256 + n) * 8 + (size_t)(tid & 1) * 4;
    size_t au = ((size_t)(128 + (tid >> 1)) * 256 + n) * 8 + (size_t)(tid & 1) * 4;
    *(uint2*)(lhsF + hu) = make_uint2(hw0, hw1);
    *(uint2*)(lhsF + au) = make_uint2(aw0, aw1);
}

// ---------------- k_step: bf16 MFMA GEMM + LSTM gates, 8-stage async pipeline -------
// REVERTED to the round-0 structure (global_load_lds staging; direct-reg variants
// of rounds 1-2 both regressed) with ONE change: pipeline depth 4 -> 8 LDS buffers
// (64 -> 128 KB), stage-ahead 3 -> 6 chunks, vmcnt(8) -> vmcnt(20).
// Rationale: W streams from L3 (~700-900 cy) every step; old in-flight bytes were
// 48 KB/CU -> sustainable ~60 B/cy only with zero jitter (observed ~28 B/cy
// effective vs 56 B/cy L2 port). 24 loads/wave in flight = 96 KB/CU covers ~1700 cy
// at full port rate. Everything else byte-identical to the verified round-0 kernel.
__global__ __launch_bounds__(256) void k_step(
    const unsigned short* __restrict__ lhsF,
    const unsigned short* __restrict__ xFt,   // xF + t*262144
    const unsigned short* __restrict__ Wsw,
    const float* __restrict__ b,
    float* __restrict__ c,
    float* __restrict__ out_t) {              // out + t*HH, row stride TT*HH
    const int nj = blockIdx.x, mi = blockIdx.y;
    const int tid = threadIdx.x;
    const int lane = tid & 63, wave = tid >> 6;
    const int wm = wave & 1, wn = wave >> 1;
    const int l15 = lane & 15, quad = lane >> 4;
    const int waveBase = tid & ~63;

    // 8 buffers x (A 4096 shorts | B 4096 shorts) = 128 KB
    __shared__ __align__(16) unsigned short lds[8 * 8192];

    floatx4 acc[2][2];
#pragma unroll
    for (int mt = 0; mt < 2; ++mt)
#pragma unroll
        for (int nt = 0; nt < 2; ++nt) acc[mt][nt] = (floatx4)0.f;

    const unsigned short* wTile = Wsw + (size_t)nj * (48 * 512 * 8);

    auto stage = [&](int kc, int buf) {
        unsigned short* la = lds + (size_t)buf * 8192;
        unsigned short* lb = la + 4096;
        const unsigned short* as_ = (kc < 32)
            ? lhsF + ((size_t)(kc * 8) * 256 + (size_t)mi * 64) * 8
            : xFt + ((size_t)((kc - 32) * 8) * 256 + (size_t)mi * 64) * 8;
#pragma unroll
        for (int i = 0; i < 2; ++i) {
            int idx = i * 256 + tid;
            int kq = idx >> 6, mm = idx & 63;
            async_copy16(as_ + ((size_t)kq * 256 + mm) * 8,
                         la + (size_t)(i * 256 + waveBase) * 8);
        }
        const unsigned short* bs = wTile + (size_t)kc * 512 * 8;
#pragma unroll
        for (int i = 0; i < 2; ++i) {
            int idx = i * 256 + tid;
            async_copy16(bs + (size_t)idx * 8,
                         lb + (size_t)(i * 256 + waveBase) * 8);
        }
    };

    auto compute = [&](int buf) {
        const unsigned short* la = lds + (size_t)buf * 8192;
        const unsigned short* lb = la + 4096;
#pragma unroll
        for (int ks = 0; ks < 2; ++ks) {
            const int kqq = ks * 4 + quad;
            short8 af[2], bfr[2];
#pragma unroll
            for (int mt = 0; mt < 2; ++mt)
                af[mt] = *(const short8*)(la + (size_t)(kqq * 64 + wm * 32 + mt * 16 + l15) * 8);
#pragma unroll
            for (int nt = 0; nt < 2; ++nt)
                bfr[nt] = *(const short8*)(lb + (size_t)(kqq * 64 + wn * 32 + nt * 16 + l15) * 8);
#pragma unroll
            for (int mt = 0; mt < 2; ++mt)
#pragma unroll
                for (int nt = 0; nt < 2; ++nt)
                    acc[mt][nt] = __builtin_amdgcn_mfma_f32_16x16x32_bf16(
                        af[mt], bfr[nt], acc[mt][nt], 0, 0, 0);
        }
    };

    stage(0, 0);
    stage(1, 1);
    stage(2, 2);
    stage(3, 3);
    stage(4, 4);
    stage(5, 5);  // 24 loads/wave outstanding = 96 KB/CU in flight

#pragma unroll 4
    for (int kc = 0; kc < 42; ++kc) {
        // wait until chunk kc's 4 loads retired (kc+1..kc+5 stay in flight)
        asm volatile("s_waitcnt vmcnt(20)\n\ts_barrier" ::: "memory");
        stage(kc + 6, (kc + 6) & 7);
        compute(kc & 7);
    }
    asm volatile("s_waitcnt vmcnt(20)\n\ts_barrier" ::: "memory");
    compute(42 & 7);
    asm volatile("s_waitcnt vmcnt(16)\n\ts_barrier" ::: "memory");
    compute(43 & 7);
    asm volatile("s_waitcnt vmcnt(12)\n\ts_barrier" ::: "memory");
    compute(44 & 7);
    asm volatile("s_waitcnt vmcnt(8)\n\ts_barrier" ::: "memory");
    compute(45 & 7);
    asm volatile("s_waitcnt vmcnt(4)\n\ts_barrier" ::: "memory");
    compute(46 & 7);
    asm volatile("s_waitcnt vmcnt(0)\n\ts_barrier" ::: "memory");
    compute(47 & 7);

    // epilogue: exchange 64x64 fp32 partial tile through LDS, then gates + c/h
    __syncthreads();
    float* asF = (float*)lds;
#pragma unroll
    for (int mt = 0; mt < 2; ++mt)
#pragma unroll
        for (int nt = 0; nt < 2; ++nt)
#pragma unroll
            for (int r = 0; r < 4; ++r) {
                int row = wm * 32 + mt * 16 + quad * 4 + r;
                int cc = wn * 32 + nt * 16 + l15;
                asF[row * 64 + cc] = acc[mt][nt][r];
            }
    __syncthreads();

    const int j15 = tid & 15;
    const int jj = nj * 16 + j15;
    const float bi = b[jj], bf_ = b[1024 + jj], bo = b[2048 + jj], bg = b[3072 + jj];
#pragma unroll
    for (int i = 0; i < 4; ++i) {
        int cell = i * 256 + tid;
        int row = cell >> 4;
        float ai  = asF[row * 64 + j15]      + bi;
        float af2 = asF[row * 64 + 16 + j15] + bf_;
        float ao  = asF[row * 64 + 32 + j15] + bo;
        float ag  = asF[row * 64 + 48 + j15] + bg;
        float iv = 1.f / (1.f + __expf(-ai));
        float fv = 1.f / (1.f + __expf(-af2));
        float ov = 1.f / (1.f + __expf(-ao));
        float gv = 1.f - 2.f / (__expf(2.f * ag) + 1.f);
        int n = mi * 64 + row;
        size_t ci = (size_t)n * HH + jj;
        float cold = c[ci];
        float cn = fv * cold + iv * gv;
        c[ci] = cn;
        float th = 1.f - 2.f / (__expf(2.f * cn) + 1.f);
        out_t[(size_t)n * (TT * HH) + jj] = ov * th;
    }
}

extern "C" void kernel_launch(void* const* d_in, const int* in_sizes, int n_in,
                              void* d_out, int out_size, void* d_ws, size_t ws_size,
                              hipStream_t stream) {
    const float* x     = (const float*)d_in[0];
    const float* A     = (const float*)d_in[1];
    const float* Wx    = (const float*)d_in[2];
    const float* Wh    = (const float*)d_in[3];
    const float* Wattn = (const float*)d_in[4];
    const float* b     = (const float*)d_in[5];
    float* out = (float*)d_out;

    char* w = (char*)d_ws;
    unsigned short* Wsw  = (unsigned short*)(w);                 // 25,165,824 B
    unsigned short* xF   = (unsigned short*)(w + 25165824);      // 33,554,432 B
    unsigned short* lhsF = (unsigned short*)(w + 58720256);      //  1,048,576 B
    unsigned short* Abf  = (unsigned short*)(w + 59768832);      //  8,388,608 B
    float* h0            = (float*)(w + 68157440);               //  1,048,576 B
    float* c             = (float*)(w + 69206016);               //  1,048,576 B

    k_convW<<<6144, 256, 0, stream>>>(Wh, Wattn, Wx, Wsw);
    k_convX<<<1024, 256, 0, stream>>>(x, xF);
    k_convA_init<<<1024, 256, 0, stream>>>(A, Abf, h0, c);

    for (int t = 0; t < TT; ++t) {
        const float* hprev = (t == 0) ? h0 : out + (size_t)(t - 1) * HH;
        int hstride = (t == 0) ? HH : TT * HH;
        k_attn<<<NB, 256, 0, stream>>>(Abf, hprev, hstride, lhsF);
        k_step<<<dim3(64, 4), 256, 0, stream>>>(
            lhsF, xF + (size_t)t * 262144, Wsw, b, c, out + (size_t)t * HH);
    }
}